// Round 1
// 1998.879 us; speedup vs baseline: 1.0941x; 1.0941x over previous
//
#include <hip/hip_runtime.h>
#include <stdint.h>

// Problem constants
#define B_  4096
#define H_  1024
#define C_  64
#define N_  786
#define NP_ 896          // N padded to 8 waves * 112
#define J_  (C_ * N_)    // 50304
#define BM_ 64
#define BK_ 32
#define WR_ 112          // B rows per wave

typedef __attribute__((ext_vector_type(4))) float f32x4;
typedef __attribute__((ext_vector_type(8))) short bf16x8;

// RNE float -> bf16
__device__ __forceinline__ unsigned short f2bf(float f) {
    union { float f; unsigned u; } v; v.f = f;
    unsigned r = v.u + 0x7fffu + ((v.u >> 16) & 1u);
    return (unsigned short)(r >> 16);
}

__device__ __forceinline__ void gload_lds16(const void* g, void* l) {
    __builtin_amdgcn_global_load_lds(
        (const __attribute__((address_space(1))) uint32_t*)g,
        (__attribute__((address_space(3))) uint32_t*)l,
        16, 0, 0);
}

// ---------------- inputs fp32 -> bf16 ----------------
__global__ void k_cast_in(const float* __restrict__ in, unsigned short* __restrict__ out) {
    int i = blockIdx.x * blockDim.x + threadIdx.x;   // over B_*H_/4
    float4 v = ((const float4*)in)[i];
    ushort4 o;
    o.x = f2bf(v.x); o.y = f2bf(v.y); o.z = f2bf(v.z); o.w = f2bf(v.w);
    ((ushort4*)out)[i] = o;
}

// ------- W_bottom [C,H,786] fp32 -> W' [C,896,1024] bf16 (transpose + pad) -------
__global__ void k_wt(const float* __restrict__ w, unsigned short* __restrict__ wt) {
    __shared__ float t[32][33];
    const int c  = blockIdx.z;
    const int h0 = blockIdx.y * 32;
    const int n0 = blockIdx.x * 32;
    const int tx = threadIdx.x, ty = threadIdx.y;
    #pragma unroll
    for (int i = 0; i < 4; ++i) {
        int h = h0 + ty + i * 8;
        int n = n0 + tx;
        float v = (n < N_) ? w[(c * H_ + h) * N_ + n] : 0.0f;
        t[ty + i * 8][tx] = v;
    }
    __syncthreads();
    #pragma unroll
    for (int i = 0; i < 4; ++i) {
        int n = n0 + ty + i * 8;
        int h = h0 + tx;
        wt[((size_t)c * NP_ + n) * H_ + h] = f2bf(t[tx][ty + i * 8]);
    }
}

// ---------------- top gating softmax: one wave per row ----------------
__global__ void k_top(const float* __restrict__ in, const float* __restrict__ wt,
                      const float* __restrict__ bt, float* __restrict__ top) {
    const int b    = blockIdx.x * 4 + (threadIdx.x >> 6);
    const int lane = threadIdx.x & 63;
    const float* row = in + (size_t)b * H_;
    float acc = bt[lane];
    #pragma unroll 8
    for (int h = 0; h < H_; ++h)
        acc = fmaf(row[h], wt[h * C_ + lane], acc);
    float m = acc;
    for (int d = 32; d; d >>= 1) m = fmaxf(m, __shfl_xor(m, d));
    float e = __expf(acc - m);
    float s = e;
    for (int d = 32; d; d >>= 1) s += __shfl_xor(s, d);
    top[b * C_ + lane] = e / s;
}

// ---------------- fused GEMM + segment softmax + scale ----------------
// grid: (B_/BM_, C_)  block: 512 (8 waves)
// Barrier-free K-loop: each wave owns its 112 B-rows (wave-private LDS double
// buffer, staged via global_load_lds with pre-swizzled source), A fragments
// register-prefetched directly from global (L1-served, identical across waves).
// Sync inside the loop is per-wave counted s_waitcnt vmcnt only.
__global__ __launch_bounds__(512, 2) void k_main(
    const unsigned short* __restrict__ A,   // [B_,H_] bf16
    const unsigned short* __restrict__ W,   // [C_,NP_,H_] bf16 (n-major, k contiguous)
    const float* __restrict__ top,          // [B_,C_]
    const float* __restrict__ bb,           // b_bottom [C_,N_]
    float* __restrict__ out)                // [B_,J_]
{
    __shared__ unsigned short sB[2][8][WR_ * BK_];   // 2 bufs x 8 waves x 7168 B = 112 KB
    __shared__ float sSum[8 * BM_];
    __shared__ float sScale[BM_];

    const int tid  = threadIdx.x;
    const int w    = tid >> 6;
    const int l    = tid & 63;
    const int b0   = blockIdx.x * BM_;
    const int c    = blockIdx.y;
    const int ar   = l & 15;      // fragment row/col within 16
    const int aq   = l >> 4;      // k-group 0..3

    f32x4 acc[7][4];
    #pragma unroll
    for (int j = 0; j < 7; ++j)
        #pragma unroll
        for (int mt = 0; mt < 4; ++mt)
            acc[j][mt] = (f32x4)0.0f;

    // ---- B staging: pre-swizzled per-lane global source (rule 21: source
    // permutation == read permutation, involution s(o) = ((o>>7)&7)<<4) ----
    // lane l linear LDS dest (within wave region, per 16-row j-tile): row l>>2, chunk l&3.
    // swizzled source element: row/chunk below.
    const int srcRow = ((l >> 2) & 14) | (((l >> 2) ^ (l >> 5)) & 1);
    const int srcQ   = (l & 3) ^ ((l >> 3) & 3);
    const unsigned short* gB = W + ((size_t)c * NP_ + w * WR_ + srcRow) * H_ + srcQ * 8;

    // ---- A fragments: direct per-lane global loads (same for all waves -> L1) ----
    const unsigned short* gA = A + (size_t)(b0 + ar) * H_ + aq * 8;

    unsigned short* lB0 = &sB[0][w][0];
    unsigned short* lB1 = &sB[1][w][0];

    bf16x8 aC[4], aN[4];

    // ---- prologue: tile 0 -> buf0 + aC ----
    #pragma unroll
    for (int j = 0; j < 7; ++j) gload_lds16(gB + j * (16 * H_), lB0 + j * 512);
    #pragma unroll
    for (int mt = 0; mt < 4; ++mt) aC[mt] = *(const bf16x8*)(gA + mt * (16 * H_));

    const unsigned short* gBp = gB + BK_;
    const unsigned short* gAp = gA + BK_;

    // One K-step: prefetch tile kt+1 (B -> LRS LDS buf, A -> ANXT regs), then
    // counted-vmcnt wait for tile kt's B, swizzled ds_read + 28 MFMA.
    // vmcnt(11) = exactly this step's 11 in-flight loads; guarantees all of the
    // previous step's loads (incl. B[kt]) have retired regardless of intra-step
    // issue order.
#define KSTEP(LRD, LST, ACUR, ANXT)                                              \
    {                                                                            \
        _Pragma("unroll")                                                        \
        for (int j = 0; j < 7; ++j) gload_lds16(gBp + j * (16 * H_), (LST) + j * 512); \
        _Pragma("unroll")                                                        \
        for (int mt = 0; mt < 4; ++mt) ANXT[mt] = *(const bf16x8*)(gAp + mt * (16 * H_)); \
        gBp += BK_; gAp += BK_;                                                  \
        asm volatile("s_waitcnt vmcnt(11)" ::: "memory");                        \
        _Pragma("unroll")                                                        \
        for (int j = 0; j < 7; ++j) {                                            \
            const int nl = j * 16 + ar;                                          \
            const int phys = ((nl << 6) | (aq << 4)) ^ (((nl >> 1) & 7) << 4);   \
            bf16x8 bF = *(const bf16x8*)((const char*)(LRD) + phys);             \
            _Pragma("unroll")                                                    \
            for (int mt = 0; mt < 4; ++mt)                                       \
                acc[j][mt] = __builtin_amdgcn_mfma_f32_16x16x32_bf16(ACUR[mt], bF, acc[j][mt], 0, 0, 0); \
        }                                                                        \
    }

    #pragma unroll 1
    for (int t = 0; t < 15; ++t) {
        KSTEP(lB0, lB1, aC, aN)    // kt = 2t   (reads buf0, stages buf1)
        KSTEP(lB1, lB0, aN, aC)    // kt = 2t+1 (reads buf1, stages buf0)
    }
    KSTEP(lB0, lB1, aC, aN)        // kt = 30

    // kt = 31: read buf1 with aN, no prefetch; drain all loads.
    asm volatile("s_waitcnt vmcnt(0)" ::: "memory");
    #pragma unroll
    for (int j = 0; j < 7; ++j) {
        const int nl = j * 16 + ar;
        const int phys = ((nl << 6) | (aq << 4)) ^ (((nl >> 1) & 7) << 4);
        bf16x8 bF = *(const bf16x8*)((const char*)lB1 + phys);
        #pragma unroll
        for (int mt = 0; mt < 4; ++mt)
            acc[j][mt] = __builtin_amdgcn_mfma_f32_16x16x32_bf16(aN[mt], bF, acc[j][mt], 0, 0, 0);
    }
#undef KSTEP

    // ---- epilogue: exp, segment-sum over n, scale, store ----
    float psum[4][4];
    #pragma unroll
    for (int mt = 0; mt < 4; ++mt)
        #pragma unroll
        for (int r = 0; r < 4; ++r) psum[mt][r] = 0.0f;

    #pragma unroll
    for (int j = 0; j < 7; ++j) {
        int n = w * WR_ + j * 16 + ar;
        bool ok = (n < N_);
        float bias = ok ? bb[c * N_ + n] : 0.0f;
        #pragma unroll
        for (int mt = 0; mt < 4; ++mt)
            #pragma unroll
            for (int r = 0; r < 4; ++r) {
                float e = ok ? __expf(acc[j][mt][r] + bias) : 0.0f;
                acc[j][mt][r] = e;
                psum[mt][r] += e;
            }
    }
    // reduce across the 16 lanes (ar) that share each row
    #pragma unroll
    for (int d = 1; d < 16; d <<= 1)
        #pragma unroll
        for (int mt = 0; mt < 4; ++mt)
            #pragma unroll
            for (int r = 0; r < 4; ++r)
                psum[mt][r] += __shfl_xor(psum[mt][r], d);
    if (ar == 0) {
        #pragma unroll
        for (int mt = 0; mt < 4; ++mt)
            #pragma unroll
            for (int r = 0; r < 4; ++r)
                sSum[w * 64 + mt * 16 + aq * 4 + r] = psum[mt][r];
    }
    __syncthreads();
    if (tid < 64) {
        float s = 0.0f;
        #pragma unroll
        for (int ww = 0; ww < 8; ++ww) s += sSum[ww * 64 + tid];
        sScale[tid] = top[(b0 + tid) * C_ + c] / s;
    }
    __syncthreads();

    #pragma unroll
    for (int j = 0; j < 7; ++j) {
        int n = w * WR_ + j * 16 + ar;
        if (n < N_) {
            #pragma unroll
            for (int mt = 0; mt < 4; ++mt)
                #pragma unroll
                for (int r = 0; r < 4; ++r) {
                    int m = mt * 16 + aq * 4 + r;
                    out[(size_t)(b0 + m) * J_ + c * N_ + n] = acc[j][mt][r] * sScale[m];
                }
        }
    }
}

extern "C" void kernel_launch(void* const* d_in, const int* in_sizes, int n_in,
                              void* d_out, int out_size, void* d_ws, size_t ws_size,
                              hipStream_t stream) {
    const float* in  = (const float*)d_in[0];   // [B,H]
    const float* Wt  = (const float*)d_in[1];   // [H,C]
    const float* bt  = (const float*)d_in[2];   // [C]
    const float* Wb  = (const float*)d_in[3];   // [C,H,N]
    const float* bb  = (const float*)d_in[4];   // [C,N]
    float* out = (float*)d_out;

    // workspace carve: inputs bf16 (8 MB) | W' bf16 (112 MB) | top_probs (1 MB)
    unsigned short* inB = (unsigned short*)d_ws;
    unsigned short* WB  = inB + (size_t)B_ * H_;
    float* top          = (float*)(WB + (size_t)C_ * NP_ * H_);

    k_cast_in<<<(B_ * H_ / 4) / 256, 256, 0, stream>>>(in, inB);
    k_wt<<<dim3(NP_ / 32, H_ / 32, C_), dim3(32, 8), 0, stream>>>(Wb, WB);
    k_top<<<B_ / 4, 256, 0, stream>>>(in, Wt, bt, top);
    k_main<<<dim3(B_ / BM_, C_), 512, 0, stream>>>(inB, WB, top, bb, out);
}